// Round 1
// 291.418 us; speedup vs baseline: 1.1055x; 1.1055x over previous
//
#include <hip/hip_runtime.h>

#define BATCH 8
#define CH 128
#define HH 128
#define WW 128
#define HWSZ 16384
#define NHEADS 8
#define DHEAD 2048

typedef short bf16x8 __attribute__((ext_vector_type(8)));
typedef short bf16x4v __attribute__((ext_vector_type(4)));
typedef float f32x4 __attribute__((ext_vector_type(4)));
typedef float f32x2 __attribute__((ext_vector_type(2)));
typedef _Float16 f16x8 __attribute__((ext_vector_type(8)));
typedef _Float16 f16x4 __attribute__((ext_vector_type(4)));

static __device__ inline unsigned short f2bf(float f) {
    unsigned u = __builtin_bit_cast(unsigned, f);
    u += 0x7fff + ((u >> 16) & 1);          // round-to-nearest-even
    return (unsigned short)(u >> 16);
}

// ---------------- Kernel 0: build Toeplitz B-fragments for dwconv MFMA --------
// Tp[c][m][lane][e] fp16, m = conv*9+dy (conv 0=q,1=k,2=v), laid out exactly as
// the mfma_f32_16x16x32_f16 B-fragment: lane holds B[k=(lane>>4)*8+e][j=lane&15],
// B[k][j] = w[c][dy*9 + (k-j)] for k-j in [0,8], else 0.
__global__ __launch_bounds__(256) void toeplitz_prep_kernel(
    const float* __restrict__ wq, const float* __restrict__ wk,
    const float* __restrict__ wv, _Float16* __restrict__ Tp)
{
    const int g = blockIdx.x * 256 + threadIdx.x;   // 128*27*64 = 221184
    const int c    = g / 1728;                      // 27*64
    const int rem  = g - c * 1728;
    const int m    = rem >> 6;
    const int lane = rem & 63;
    const int conv = m / 9;
    const int dy   = m - conv * 9;
    const float* w = (conv == 0) ? wq : ((conv == 1) ? wk : wv);
    const int j    = lane & 15;
    const int kb   = (lane >> 4) << 3;
    f16x8 h;
    #pragma unroll
    for (int e = 0; e < 8; ++e) {
        const int d = kb + e - j;
        h[e] = (d >= 0 && d <= 8) ? (_Float16)w[c * 81 + dy * 9 + d]
                                  : (_Float16)0.f;
    }
    *(f16x8*)&Tp[(size_t)g * 8] = h;
}

// ---------------- Kernel 1: depthwise 9x9 conv -> Q,K,V via MFMA Toeplitz -----
// One block per (b,c). Image staged in LDS as fp16 with 4-halo zero padding.
// Per wave supergroup (16 y x 32 x): 9 dy steps, each = 2 aligned ds_read_b128
// A-fragments (A[i][k] = img[y0+i+dy][x0+k]) x 3 conv MFMAs, dy-sum chained in
// the fp32 C accumulator. B-fragments (27) register-resident for the block.
__global__ __launch_bounds__(256) void dwconv_qkv_mfma_kernel(
    const float* __restrict__ x,
    const float* __restrict__ bq, const float* __restrict__ bk,
    const float* __restrict__ bv,
    const _Float16* __restrict__ Tp,
    unsigned short* __restrict__ Qb, unsigned short* __restrict__ Kb,
    unsigned short* __restrict__ Vb)
{
    const int bc = blockIdx.x;
    const int b  = bc >> 7;
    const int c  = bc & (CH - 1);

    __shared__ _Float16 img[136][144];   // [y+4][x+4], zero halo, 39168 B

    const int tid  = threadIdx.x;
    const int wave = tid >> 6;
    const int lane = tid & 63;
    const int lx   = lane & 15;
    const int qd   = lane >> 4;

    // B-fragments: issue the 27 coalesced 16B loads early (latency hides under staging)
    f16x8 Btp[27];
    const _Float16* tp = Tp + (size_t)c * 13824 + (size_t)lane * 8;
    #pragma unroll
    for (int m = 0; m < 27; ++m)
        Btp[m] = *(const f16x8*)(tp + (size_t)m * 512);

    // zero entire LDS image (covers halo), then fill interior
    {
        f16x8 z = {0, 0, 0, 0, 0, 0, 0, 0};
        _Float16* flat = &img[0][0];
        for (int i = tid; i < 2448; i += 256)       // 136*144/8
            *(f16x8*)&flat[i * 8] = z;
    }
    __syncthreads();
    const float* xp = x + (size_t)bc * HWSZ;
    for (int i = tid; i < 4096; i += 256) {
        const float4 v = *(const float4*)&xp[i * 4];
        const int y  = i >> 5;
        const int xc = (i & 31) << 2;
        f16x4 h = {(_Float16)v.x, (_Float16)v.y, (_Float16)v.z, (_Float16)v.w};
        *(f16x4*)&img[y + 4][xc + 4] = h;
    }
    __syncthreads();

    const float bqv = bq[c], bkv = bk[c], bvv = bv[c];

    #pragma unroll 1
    for (int t = 0; t < 8; ++t) {
        const int sg = t * 4 + wave;                // 32 supergroups / block
        const int yg = sg >> 2;
        const int y0 = yg << 4;
        const int x0 = (sg & 3) << 5;

        f32x4 aq0 = {bqv, bqv, bqv, bqv}, aq1 = aq0;
        f32x4 ak0 = {bkv, bkv, bkv, bkv}, ak1 = ak0;
        f32x4 av0 = {bvv, bvv, bvv, bvv}, av1 = av0;

        const _Float16* rp = &img[y0 + lx][x0 + (qd << 3)];
        #pragma unroll
        for (int dy = 0; dy < 9; ++dy) {
            const f16x8 a0 = *(const f16x8*)rp;
            const f16x8 a1 = *(const f16x8*)(rp + 16);
            rp += 144;
            aq0 = __builtin_amdgcn_mfma_f32_16x16x32_f16(a0, Btp[dy],      aq0, 0, 0, 0);
            aq1 = __builtin_amdgcn_mfma_f32_16x16x32_f16(a1, Btp[dy],      aq1, 0, 0, 0);
            ak0 = __builtin_amdgcn_mfma_f32_16x16x32_f16(a0, Btp[9 + dy],  ak0, 0, 0, 0);
            ak1 = __builtin_amdgcn_mfma_f32_16x16x32_f16(a1, Btp[9 + dy],  ak1, 0, 0, 0);
            av0 = __builtin_amdgcn_mfma_f32_16x16x32_f16(a0, Btp[18 + dy], av0, 0, 0, 0);
            av1 = __builtin_amdgcn_mfma_f32_16x16x32_f16(a1, Btp[18 + dy], av1, 0, 0, 0);
        }

        // C layout: lane holds D[y = qd*4+r][x = lx]; t = (y&15)*128 + x, head = yg
        const size_t base = ((size_t)(b * 8 + yg) * CH + c) * DHEAD
                          + (size_t)(qd << 2) * WW + x0 + lx;
        #pragma unroll
        for (int r = 0; r < 4; ++r) {
            Qb[base + r * WW]      = f2bf(aq0[r]);
            Qb[base + r * WW + 16] = f2bf(aq1[r]);
            Kb[base + r * WW]      = f2bf(ak0[r]);
            Kb[base + r * WW + 16] = f2bf(ak1[r]);
            Vb[base + r * WW]      = f2bf(av0[r]);
            Vb[base + r * WW + 16] = f2bf(av1[r]);
        }
    }
}

// ---------------- Kernel 2: Spart[split][bh] = Q_chunk K_chunk^T via MFMA ------
__global__ __launch_bounds__(256) void qk_mfma_kernel(
    const unsigned short* __restrict__ Qb, const unsigned short* __restrict__ Kb,
    float* __restrict__ Spart)
{
    const int blk   = blockIdx.x;
    const int split = blk & 7;
    const int bh    = blk >> 3;
    const int t0    = split * 256;

    __shared__ unsigned short Qs[128][72];
    __shared__ unsigned short Ks[128][72];

    const int tid  = threadIdx.x;
    const int wave = tid >> 6;
    const int lane = tid & 63;
    const int lx   = lane & 15;
    const int qd   = lane >> 4;
    const int m0   = (wave & 1) * 64;
    const int n0   = (wave >> 1) * 64;

    f32x4 acc[4][4];
    #pragma unroll
    for (int mi = 0; mi < 4; ++mi)
        #pragma unroll
        for (int ni = 0; ni < 4; ++ni) acc[mi][ni] = (f32x4){0.f, 0.f, 0.f, 0.f};

    const unsigned short* Qp = Qb + (size_t)bh * CH * DHEAD;
    const unsigned short* Kp = Kb + (size_t)bh * CH * DHEAD;

    #pragma unroll 1
    for (int tc = 0; tc < 256; tc += 64) {
        __syncthreads();
        for (int i = tid; i < 1024; i += 256) {
            const int r  = i >> 3;
            const int cl = (i & 7) << 3;
            *(bf16x8*)&Qs[r][cl] = *(const bf16x8*)&Qp[(size_t)r * DHEAD + t0 + tc + cl];
            *(bf16x8*)&Ks[r][cl] = *(const bf16x8*)&Kp[(size_t)r * DHEAD + t0 + tc + cl];
        }
        __syncthreads();
        #pragma unroll
        for (int ki = 0; ki < 2; ++ki) {
            const int kc = ki * 32 + qd * 8;
            bf16x8 a[4], bv[4];
            #pragma unroll
            for (int mi = 0; mi < 4; ++mi)
                a[mi] = *(const bf16x8*)&Qs[m0 + mi * 16 + lx][kc];
            #pragma unroll
            for (int ni = 0; ni < 4; ++ni)
                bv[ni] = *(const bf16x8*)&Ks[n0 + ni * 16 + lx][kc];
            #pragma unroll
            for (int mi = 0; mi < 4; ++mi)
                #pragma unroll
                for (int ni = 0; ni < 4; ++ni)
                    acc[mi][ni] = __builtin_amdgcn_mfma_f32_16x16x32_bf16(
                        a[mi], bv[ni], acc[mi][ni], 0, 0, 0);
        }
    }
    float* Sp = Spart + ((size_t)split * 64 + bh) * (CH * CH);
    #pragma unroll
    for (int mi = 0; mi < 4; ++mi)
        #pragma unroll
        for (int r = 0; r < 4; ++r) {
            const int c = m0 + mi * 16 + qd * 4 + r;
            #pragma unroll
            for (int ni = 0; ni < 4; ++ni)
                Sp[c * CH + n0 + ni * 16 + lx] = acc[mi][ni][r];
        }
}

// ---------------- Kernel 3: reduce 8 partials + row softmax -> P bf16 [c][e] ---
__global__ __launch_bounds__(256) void softmax_kernel(
    const float* __restrict__ Spart, unsigned short* __restrict__ Pb)
{
    const int row  = blockIdx.x * 4 + (threadIdx.x >> 6);   // bh*128 + c
    const int lane = threadIdx.x & 63;
    float v0 = 0.f, v1 = 0.f;
    #pragma unroll
    for (int s = 0; s < 8; ++s) {
        const float* Sp = Spart + (size_t)s * 64 * CH * CH + (size_t)row * CH;
        v0 += Sp[lane];
        v1 += Sp[lane + 64];
    }
    v0 *= 0.0078125f; v1 *= 0.0078125f;
    float m = fmaxf(v0, v1);
    #pragma unroll
    for (int off = 32; off > 0; off >>= 1) m = fmaxf(m, __shfl_down(m, off));
    m = __shfl(m, 0);
    const float e0 = __expf(v0 - m);
    const float e1 = __expf(v1 - m);
    float s = e0 + e1;
    #pragma unroll
    for (int off = 32; off > 0; off >>= 1) s += __shfl_down(s, off);
    s = __shfl(s, 0);
    const float inv = 1.f / s;
    Pb[(size_t)row * CH + lane]      = f2bf(e0 * inv);
    Pb[(size_t)row * CH + lane + 64] = f2bf(e1 * inv);
}

// ---------------- Kernel 4: A = P V via MFMA, out At[b][p][ci] bf16 ------------
__global__ __launch_bounds__(256) void pv_mfma_kernel(
    const unsigned short* __restrict__ Pb, const unsigned short* __restrict__ Vb,
    unsigned short* __restrict__ At)
{
    const int blk = blockIdx.x;
    const int t0  = (blk & 15) << 7;
    const int bh  = blk >> 4;

    __shared__ __align__(16) char smem[69632];
    unsigned short (*Ps)[136] = (unsigned short(*)[136])smem;            // 34816 B
    unsigned short (*Vs)[136] = (unsigned short(*)[136])(smem + 34816);  // 34816 B
    float (*So)[132] = (float(*)[132])smem;                              // reused

    const int tid  = threadIdx.x;
    const int wave = tid >> 6;
    const int lane = tid & 63;
    const int lx   = lane & 15;
    const int qd   = lane >> 4;
    const int m0   = (wave & 1) * 64;      // c tile
    const int n0   = (wave >> 1) * 64;     // t tile

    const unsigned short* Pp = Pb + (size_t)bh * CH * CH;
    const unsigned short* Vp = Vb + (size_t)bh * CH * DHEAD;

    for (int i = tid; i < 2048; i += 256) {
        const int r  = i >> 4;
        const int cl = (i & 15) << 3;
        *(bf16x8*)&Ps[r][cl] = *(const bf16x8*)&Pp[(size_t)r * CH + cl];
    }
    for (int i = tid; i < 2048; i += 256) {
        const int e   = i & 127;
        const int tc8 = (i >> 7) << 3;
        const bf16x8 vv = *(const bf16x8*)&Vp[(size_t)e * DHEAD + t0 + tc8];
        #pragma unroll
        for (int j = 0; j < 8; ++j) Vs[tc8 + j][e] = (unsigned short)vv[j];
    }
    __syncthreads();

    f32x4 acc[4][4];
    #pragma unroll
    for (int mi = 0; mi < 4; ++mi)
        #pragma unroll
        for (int ni = 0; ni < 4; ++ni) acc[mi][ni] = (f32x4){0.f, 0.f, 0.f, 0.f};

    #pragma unroll
    for (int ki = 0; ki < 4; ++ki) {
        const int kc = ki * 32 + qd * 8;
        bf16x8 a[4], bv[4];
        #pragma unroll
        for (int mi = 0; mi < 4; ++mi)
            a[mi] = *(const bf16x8*)&Ps[m0 + mi * 16 + lx][kc];
        #pragma unroll
        for (int ni = 0; ni < 4; ++ni)
            bv[ni] = *(const bf16x8*)&Vs[n0 + ni * 16 + lx][kc];
        #pragma unroll
        for (int mi = 0; mi < 4; ++mi)
            #pragma unroll
            for (int ni = 0; ni < 4; ++ni)
                acc[mi][ni] = __builtin_amdgcn_mfma_f32_16x16x32_bf16(
                    a[mi], bv[ni], acc[mi][ni], 0, 0, 0);
    }

    __syncthreads();
    #pragma unroll
    for (int mi = 0; mi < 4; ++mi)
        #pragma unroll
        for (int ni = 0; ni < 4; ++ni)
            #pragma unroll
            for (int r = 0; r < 4; ++r)
                So[n0 + ni * 16 + lx][m0 + mi * 16 + qd * 4 + r] = acc[mi][ni][r];
    __syncthreads();

    const int t  = tid >> 1;
    const int ch = (tid & 1) * 64;
    const size_t orow = (((size_t)(bh >> 3) * HWSZ) + (size_t)(bh & 7) * DHEAD + t0 + t) * CH + ch;
    #pragma unroll
    for (int j = 0; j < 8; ++j) {
        const float4 f0 = *(const float4*)&So[t][ch + j * 8];
        const float4 f1 = *(const float4*)&So[t][ch + j * 8 + 4];
        bf16x8 h;
        h[0] = (short)f2bf(f0.x); h[1] = (short)f2bf(f0.y);
        h[2] = (short)f2bf(f0.z); h[3] = (short)f2bf(f0.w);
        h[4] = (short)f2bf(f1.x); h[5] = (short)f2bf(f1.y);
        h[6] = (short)f2bf(f1.z); h[7] = (short)f2bf(f1.w);
        *(bf16x8*)&At[orow + j * 8] = h;
    }
}

// ---------------- Kernel 5a: weight prep wo fp32 -> Wt[tap][co][ci] bf16 ------
__global__ __launch_bounds__(256) void wprep_kernel(
    const float* __restrict__ wo, unsigned short* __restrict__ Wt)
{
    const int i = blockIdx.x * 256 + threadIdx.x;     // 9*128*128 = 147456
    const int tap = i >> 14;
    const int rem = i & 16383;
    const int co  = rem >> 7;
    const int ci  = rem & 127;
    Wt[i] = f2bf(wo[(size_t)(co * CH + ci) * 9 + tap]);
}

// ---------------- Kernel 5b: 3x3 dense conv via bf16 MFMA implicit GEMM -------
__global__ __launch_bounds__(256, 3) void conv3x3_mfma_kernel(
    const unsigned short* __restrict__ At, const unsigned short* __restrict__ Wt,
    const float* __restrict__ bo, float* __restrict__ out)
{
    const int blk = blockIdx.x;
    const int y   = blk & (HH - 1);
    const int b   = blk >> 7;

    __shared__ unsigned short sA[130][136];   // x in -1..128 (+1 offset)
    __shared__ unsigned short sW[128][72];

    const int tid  = threadIdx.x;
    const int wave = tid >> 6;
    const int lane = tid & 63;
    const int lx   = lane & 15;
    const int qd   = lane >> 4;
    const int m0   = (wave & 1) * 64;
    const int n0   = (wave >> 1) * 64;

    for (int i = tid; i < 272; i += 256) {
        const int r   = (i < 136) ? 0 : 129;
        const int col = (i < 136) ? i : (i - 136);
        sA[r][col] = 0;
    }

    f32x4 acc[4][4];
    #pragma unroll
    for (int mi = 0; mi < 4; ++mi) {
        f32x4 bv;
        #pragma unroll
        for (int r = 0; r < 4; ++r) bv[r] = bo[m0 + mi * 16 + qd * 4 + r];
        #pragma unroll
        for (int ni = 0; ni < 4; ++ni) acc[mi][ni] = bv;
    }

    const size_t abase = (size_t)b * HWSZ * CH;

    for (int dy = 0; dy < 3; ++dy) {
        const int gy = y + dy - 1;
        __syncthreads();
        if ((unsigned)gy < HH) {
            const unsigned short* row = At + abase + (size_t)gy * WW * CH;
            for (int i = tid; i < 2048; i += 256) {
                const int xx  = i >> 4;
                const int cc8 = (i & 15) << 3;
                *(float4*)&sA[xx + 1][cc8] = *(const float4*)&row[xx * CH + cc8];
            }
        } else {
            const float4 z = make_float4(0.f, 0.f, 0.f, 0.f);
            for (int i = tid; i < 2048; i += 256) {
                const int xx  = i >> 4;
                const int cc8 = (i & 15) << 3;
                *(float4*)&sA[xx + 1][cc8] = z;
            }
        }
        for (int dx = 0; dx < 3; ++dx) {
            const int tap = dy * 3 + dx;
            #pragma unroll 1
            for (int kh = 0; kh < 2; ++kh) {
                if (dx | kh) __syncthreads();
                const unsigned short* wt = Wt + (size_t)tap * CH * CH + kh * 64;
                for (int i = tid; i < 1024; i += 256) {
                    const int co  = i >> 3;
                    const int cc8 = (i & 7) << 3;
                    *(float4*)&sW[co][cc8] = *(const float4*)&wt[co * CH + cc8];
                }
                __syncthreads();
                #pragma unroll
                for (int ks = 0; ks < 2; ++ks) {
                    const int kc  = ks * 32 + qd * 8;
                    const int kca = kh * 64 + kc;
                    bf16x8 a[4], bfr[4];
                    #pragma unroll
                    for (int mi = 0; mi < 4; ++mi)
                        a[mi] = *(const bf16x8*)&sW[m0 + mi * 16 + lx][kc];
                    #pragma unroll
                    for (int ni = 0; ni < 4; ++ni)
                        bfr[ni] = *(const bf16x8*)&sA[n0 + ni * 16 + lx + dx][kca];
                    #pragma unroll
                    for (int mi = 0; mi < 4; ++mi)
                        #pragma unroll
                        for (int ni = 0; ni < 4; ++ni)
                            acc[mi][ni] = __builtin_amdgcn_mfma_f32_16x16x32_bf16(
                                a[mi], bfr[ni], acc[mi][ni], 0, 0, 0);
                }
            }
        }
    }

    const size_t obase = (size_t)b * CH * HWSZ + (size_t)y * WW;
    #pragma unroll
    for (int mi = 0; mi < 4; ++mi) {
        #pragma unroll
        for (int r = 0; r < 4; ++r) {
            const int co = m0 + mi * 16 + qd * 4 + r;
            float* orow = out + obase + (size_t)co * HWSZ;
            #pragma unroll
            for (int ni = 0; ni < 4; ++ni)
                orow[n0 + ni * 16 + lx] = acc[mi][ni][r];
        }
    }
}

extern "C" void kernel_launch(void* const* d_in, const int* in_sizes, int n_in,
                              void* d_out, int out_size, void* d_ws, size_t ws_size,
                              hipStream_t stream)
{
    const float* x  = (const float*)d_in[0];
    const float* wq = (const float*)d_in[1];
    const float* bq = (const float*)d_in[2];
    const float* wk = (const float*)d_in[3];
    const float* bk = (const float*)d_in[4];
    const float* wv = (const float*)d_in[5];
    const float* bv = (const float*)d_in[6];
    const float* wo = (const float*)d_in[7];
    const float* bo = (const float*)d_in[8];

    char* ws = (char*)d_ws;
    unsigned short* Qb    = (unsigned short*)(ws);                        // 32 MiB
    unsigned short* Kb    = (unsigned short*)(ws + (size_t)33554432);     // 32 MiB
    unsigned short* Vb    = (unsigned short*)(ws + (size_t)67108864);     // 32 MiB
    float*          Spart = (float*)        (ws + (size_t)100663296);     // 32 MiB
    unsigned short* Pb    = (unsigned short*)(ws + (size_t)134217728);    // 2 MiB
    unsigned short* At    = (unsigned short*)(ws + (size_t)136314880);    // 32 MiB -> ends 169869312
    unsigned short* Wt    = (unsigned short*)(ws + (size_t)169869312);    // 288 KiB
    // Toeplitz table reuses the head of the Spart region (3.46 MiB); it is dead
    // by the time qk_mfma_kernel writes Spart (stream-ordered).
    _Float16*       Tp    = (_Float16*)      (ws + (size_t)100663296);

    toeplitz_prep_kernel<<<864, 256, 0, stream>>>(wq, wk, wv, Tp);
    dwconv_qkv_mfma_kernel<<<BATCH * CH, 256, 0, stream>>>(x, bq, bk, bv, Tp, Qb, Kb, Vb);
    wprep_kernel<<<576, 256, 0, stream>>>(wo, Wt);
    qk_mfma_kernel<<<64 * 8, 256, 0, stream>>>(Qb, Kb, Spart);
    softmax_kernel<<<2048, 256, 0, stream>>>(Spart, Pb);
    pv_mfma_kernel<<<64 * 16, 256, 0, stream>>>(Pb, Vb, At);
    conv3x3_mfma_kernel<<<BATCH * HH, 256, 0, stream>>>(At, Wt, bo, (float*)d_out);
}

// Round 3
// 268.930 us; speedup vs baseline: 1.1979x; 1.0836x over previous
//
#include <hip/hip_runtime.h>

#define BATCH 8
#define CH 128
#define HH 128
#define WW 128
#define HWSZ 16384
#define NHEADS 8
#define DHEAD 2048

typedef short bf16x8 __attribute__((ext_vector_type(8)));
typedef short bf16x4v __attribute__((ext_vector_type(4)));
typedef float f32x4 __attribute__((ext_vector_type(4)));
typedef float f32x2 __attribute__((ext_vector_type(2)));
typedef _Float16 f16x8 __attribute__((ext_vector_type(8)));
typedef _Float16 f16x4 __attribute__((ext_vector_type(4)));

static __device__ inline unsigned short f2bf(float f) {
    unsigned u = __builtin_bit_cast(unsigned, f);
    u += 0x7fff + ((u >> 16) & 1);          // round-to-nearest-even
    return (unsigned short)(u >> 16);
}

// ---------------- Kernel 0: build Toeplitz B-fragments for dwconv MFMA --------
__global__ __launch_bounds__(256) void toeplitz_prep_kernel(
    const float* __restrict__ wq, const float* __restrict__ wk,
    const float* __restrict__ wv, _Float16* __restrict__ Tp)
{
    const int g = blockIdx.x * 256 + threadIdx.x;   // 128*27*64 = 221184
    const int c    = g / 1728;                      // 27*64
    const int rem  = g - c * 1728;
    const int m    = rem >> 6;
    const int lane = rem & 63;
    const int conv = m / 9;
    const int dy   = m - conv * 9;
    const float* w = (conv == 0) ? wq : ((conv == 1) ? wk : wv);
    const int j    = lane & 15;
    const int kb   = (lane >> 4) << 3;
    f16x8 h;
    #pragma unroll
    for (int e = 0; e < 8; ++e) {
        const int d = kb + e - j;
        h[e] = (d >= 0 && d <= 8) ? (_Float16)w[c * 81 + dy * 9 + d]
                                  : (_Float16)0.f;
    }
    *(f16x8*)&Tp[(size_t)g * 8] = h;
}

// ---------------- Kernel 1: depthwise 9x9 conv -> Q,K,V via MFMA Toeplitz -----
__global__ __launch_bounds__(256) void dwconv_qkv_mfma_kernel(
    const float* __restrict__ x,
    const float* __restrict__ bq, const float* __restrict__ bk,
    const float* __restrict__ bv,
    const _Float16* __restrict__ Tp,
    unsigned short* __restrict__ Qb, unsigned short* __restrict__ Kb,
    unsigned short* __restrict__ Vb)
{
    const int bc = blockIdx.x;
    const int b  = bc >> 7;
    const int c  = bc & (CH - 1);

    __shared__ _Float16 img[136][144];   // [y+4][x+4], zero halo, 39168 B

    const int tid  = threadIdx.x;
    const int wave = tid >> 6;
    const int lane = tid & 63;
    const int lx   = lane & 15;
    const int qd   = lane >> 4;

    f16x8 Btp[27];
    const _Float16* tp = Tp + (size_t)c * 13824 + (size_t)lane * 8;
    #pragma unroll
    for (int m = 0; m < 27; ++m)
        Btp[m] = *(const f16x8*)(tp + (size_t)m * 512);

    {
        f16x8 z = {0, 0, 0, 0, 0, 0, 0, 0};
        _Float16* flat = &img[0][0];
        for (int i = tid; i < 2448; i += 256)       // 136*144/8
            *(f16x8*)&flat[i * 8] = z;
    }
    __syncthreads();
    const float* xp = x + (size_t)bc * HWSZ;
    for (int i = tid; i < 4096; i += 256) {
        const float4 v = *(const float4*)&xp[i * 4];
        const int y  = i >> 5;
        const int xc = (i & 31) << 2;
        f16x4 h = {(_Float16)v.x, (_Float16)v.y, (_Float16)v.z, (_Float16)v.w};
        *(f16x4*)&img[y + 4][xc + 4] = h;
    }
    __syncthreads();

    const float bqv = bq[c], bkv = bk[c], bvv = bv[c];

    #pragma unroll 1
    for (int t = 0; t < 8; ++t) {
        const int sg = t * 4 + wave;                // 32 supergroups / block
        const int yg = sg >> 2;
        const int y0 = yg << 4;
        const int x0 = (sg & 3) << 5;

        f32x4 aq0 = {bqv, bqv, bqv, bqv}, aq1 = aq0;
        f32x4 ak0 = {bkv, bkv, bkv, bkv}, ak1 = ak0;
        f32x4 av0 = {bvv, bvv, bvv, bvv}, av1 = av0;

        const _Float16* rp = &img[y0 + lx][x0 + (qd << 3)];
        #pragma unroll
        for (int dy = 0; dy < 9; ++dy) {
            const f16x8 a0 = *(const f16x8*)rp;
            const f16x8 a1 = *(const f16x8*)(rp + 16);
            rp += 144;
            aq0 = __builtin_amdgcn_mfma_f32_16x16x32_f16(a0, Btp[dy],      aq0, 0, 0, 0);
            aq1 = __builtin_amdgcn_mfma_f32_16x16x32_f16(a1, Btp[dy],      aq1, 0, 0, 0);
            ak0 = __builtin_amdgcn_mfma_f32_16x16x32_f16(a0, Btp[9 + dy],  ak0, 0, 0, 0);
            ak1 = __builtin_amdgcn_mfma_f32_16x16x32_f16(a1, Btp[9 + dy],  ak1, 0, 0, 0);
            av0 = __builtin_amdgcn_mfma_f32_16x16x32_f16(a0, Btp[18 + dy], av0, 0, 0, 0);
            av1 = __builtin_amdgcn_mfma_f32_16x16x32_f16(a1, Btp[18 + dy], av1, 0, 0, 0);
        }

        const size_t base = ((size_t)(b * 8 + yg) * CH + c) * DHEAD
                          + (size_t)(qd << 2) * WW + x0 + lx;
        #pragma unroll
        for (int r = 0; r < 4; ++r) {
            Qb[base + r * WW]      = f2bf(aq0[r]);
            Qb[base + r * WW + 16] = f2bf(aq1[r]);
            Kb[base + r * WW]      = f2bf(ak0[r]);
            Kb[base + r * WW + 16] = f2bf(ak1[r]);
            Vb[base + r * WW]      = f2bf(av0[r]);
            Vb[base + r * WW + 16] = f2bf(av1[r]);
        }
    }
}

// ---------------- Kernel 2: Spart[split][bh] = Q_chunk K_chunk^T via MFMA ------
__global__ __launch_bounds__(256) void qk_mfma_kernel(
    const unsigned short* __restrict__ Qb, const unsigned short* __restrict__ Kb,
    float* __restrict__ Spart)
{
    const int blk   = blockIdx.x;
    const int split = blk & 7;
    const int bh    = blk >> 3;
    const int t0    = split * 256;

    __shared__ unsigned short Qs[128][72];
    __shared__ unsigned short Ks[128][72];

    const int tid  = threadIdx.x;
    const int wave = tid >> 6;
    const int lane = tid & 63;
    const int lx   = lane & 15;
    const int qd   = lane >> 4;
    const int m0   = (wave & 1) * 64;
    const int n0   = (wave >> 1) * 64;

    f32x4 acc[4][4];
    #pragma unroll
    for (int mi = 0; mi < 4; ++mi)
        #pragma unroll
        for (int ni = 0; ni < 4; ++ni) acc[mi][ni] = (f32x4){0.f, 0.f, 0.f, 0.f};

    const unsigned short* Qp = Qb + (size_t)bh * CH * DHEAD;
    const unsigned short* Kp = Kb + (size_t)bh * CH * DHEAD;

    #pragma unroll 1
    for (int tc = 0; tc < 256; tc += 64) {
        __syncthreads();
        for (int i = tid; i < 1024; i += 256) {
            const int r  = i >> 3;
            const int cl = (i & 7) << 3;
            *(bf16x8*)&Qs[r][cl] = *(const bf16x8*)&Qp[(size_t)r * DHEAD + t0 + tc + cl];
            *(bf16x8*)&Ks[r][cl] = *(const bf16x8*)&Kp[(size_t)r * DHEAD + t0 + tc + cl];
        }
        __syncthreads();
        #pragma unroll
        for (int ki = 0; ki < 2; ++ki) {
            const int kc = ki * 32 + qd * 8;
            bf16x8 a[4], bv[4];
            #pragma unroll
            for (int mi = 0; mi < 4; ++mi)
                a[mi] = *(const bf16x8*)&Qs[m0 + mi * 16 + lx][kc];
            #pragma unroll
            for (int ni = 0; ni < 4; ++ni)
                bv[ni] = *(const bf16x8*)&Ks[n0 + ni * 16 + lx][kc];
            #pragma unroll
            for (int mi = 0; mi < 4; ++mi)
                #pragma unroll
                for (int ni = 0; ni < 4; ++ni)
                    acc[mi][ni] = __builtin_amdgcn_mfma_f32_16x16x32_bf16(
                        a[mi], bv[ni], acc[mi][ni], 0, 0, 0);
        }
    }
    float* Sp = Spart + ((size_t)split * 64 + bh) * (CH * CH);
    #pragma unroll
    for (int mi = 0; mi < 4; ++mi)
        #pragma unroll
        for (int r = 0; r < 4; ++r) {
            const int c = m0 + mi * 16 + qd * 4 + r;
            #pragma unroll
            for (int ni = 0; ni < 4; ++ni)
                Sp[c * CH + n0 + ni * 16 + lx] = acc[mi][ni][r];
        }
}

// ---------------- Kernel 3: reduce 8 partials + row softmax -> P bf16 [c][e] ---
__global__ __launch_bounds__(256) void softmax_kernel(
    const float* __restrict__ Spart, unsigned short* __restrict__ Pb)
{
    const int row  = blockIdx.x * 4 + (threadIdx.x >> 6);   // bh*128 + c
    const int lane = threadIdx.x & 63;
    float v0 = 0.f, v1 = 0.f;
    #pragma unroll
    for (int s = 0; s < 8; ++s) {
        const float* Sp = Spart + (size_t)s * 64 * CH * CH + (size_t)row * CH;
        v0 += Sp[lane];
        v1 += Sp[lane + 64];
    }
    v0 *= 0.0078125f; v1 *= 0.0078125f;
    float m = fmaxf(v0, v1);
    #pragma unroll
    for (int off = 32; off > 0; off >>= 1) m = fmaxf(m, __shfl_down(m, off));
    m = __shfl(m, 0);
    const float e0 = __expf(v0 - m);
    const float e1 = __expf(v1 - m);
    float s = e0 + e1;
    #pragma unroll
    for (int off = 32; off > 0; off >>= 1) s += __shfl_down(s, off);
    s = __shfl(s, 0);
    const float inv = 1.f / s;
    Pb[(size_t)row * CH + lane]      = f2bf(e0 * inv);
    Pb[(size_t)row * CH + lane + 64] = f2bf(e1 * inv);
}

// ---------------- Kernel 4: A = P V via MFMA, out At[b][p][ci] bf16 ------------
__global__ __launch_bounds__(256) void pv_mfma_kernel(
    const unsigned short* __restrict__ Pb, const unsigned short* __restrict__ Vb,
    unsigned short* __restrict__ At)
{
    const int blk = blockIdx.x;
    const int t0  = (blk & 15) << 7;
    const int bh  = blk >> 4;

    __shared__ __align__(16) char smem[69632];
    unsigned short (*Ps)[136] = (unsigned short(*)[136])smem;            // 34816 B
    unsigned short (*Vs)[136] = (unsigned short(*)[136])(smem + 34816);  // 34816 B
    float (*So)[132] = (float(*)[132])smem;                              // reused

    const int tid  = threadIdx.x;
    const int wave = tid >> 6;
    const int lane = tid & 63;
    const int lx   = lane & 15;
    const int qd   = lane >> 4;
    const int m0   = (wave & 1) * 64;      // c tile
    const int n0   = (wave >> 1) * 64;     // t tile

    const unsigned short* Pp = Pb + (size_t)bh * CH * CH;
    const unsigned short* Vp = Vb + (size_t)bh * CH * DHEAD;

    for (int i = tid; i < 2048; i += 256) {
        const int r  = i >> 4;
        const int cl = (i & 15) << 3;
        *(bf16x8*)&Ps[r][cl] = *(const bf16x8*)&Pp[(size_t)r * CH + cl];
    }
    for (int i = tid; i < 2048; i += 256) {
        const int e   = i & 127;
        const int tc8 = (i >> 7) << 3;
        const bf16x8 vv = *(const bf16x8*)&Vp[(size_t)e * DHEAD + t0 + tc8];
        #pragma unroll
        for (int j = 0; j < 8; ++j) Vs[tc8 + j][e] = (unsigned short)vv[j];
    }
    __syncthreads();

    f32x4 acc[4][4];
    #pragma unroll
    for (int mi = 0; mi < 4; ++mi)
        #pragma unroll
        for (int ni = 0; ni < 4; ++ni) acc[mi][ni] = (f32x4){0.f, 0.f, 0.f, 0.f};

    #pragma unroll
    for (int ki = 0; ki < 4; ++ki) {
        const int kc = ki * 32 + qd * 8;
        bf16x8 a[4], bv[4];
        #pragma unroll
        for (int mi = 0; mi < 4; ++mi)
            a[mi] = *(const bf16x8*)&Ps[m0 + mi * 16 + lx][kc];
        #pragma unroll
        for (int ni = 0; ni < 4; ++ni)
            bv[ni] = *(const bf16x8*)&Vs[n0 + ni * 16 + lx][kc];
        #pragma unroll
        for (int mi = 0; mi < 4; ++mi)
            #pragma unroll
            for (int ni = 0; ni < 4; ++ni)
                acc[mi][ni] = __builtin_amdgcn_mfma_f32_16x16x32_bf16(
                    a[mi], bv[ni], acc[mi][ni], 0, 0, 0);
    }

    __syncthreads();
    #pragma unroll
    for (int mi = 0; mi < 4; ++mi)
        #pragma unroll
        for (int ni = 0; ni < 4; ++ni)
            #pragma unroll
            for (int r = 0; r < 4; ++r)
                So[n0 + ni * 16 + lx][m0 + mi * 16 + qd * 4 + r] = acc[mi][ni][r];
    __syncthreads();

    const int t  = tid >> 1;
    const int ch = (tid & 1) * 64;
    const size_t orow = (((size_t)(bh >> 3) * HWSZ) + (size_t)(bh & 7) * DHEAD + t0 + t) * CH + ch;
    #pragma unroll
    for (int j = 0; j < 8; ++j) {
        const float4 f0 = *(const float4*)&So[t][ch + j * 8];
        const float4 f1 = *(const float4*)&So[t][ch + j * 8 + 4];
        bf16x8 h;
        h[0] = (short)f2bf(f0.x); h[1] = (short)f2bf(f0.y);
        h[2] = (short)f2bf(f0.z); h[3] = (short)f2bf(f0.w);
        h[4] = (short)f2bf(f1.x); h[5] = (short)f2bf(f1.y);
        h[6] = (short)f2bf(f1.z); h[7] = (short)f2bf(f1.w);
        *(bf16x8*)&At[orow + j * 8] = h;
    }
}

// ---------------- Kernel 5a: weight prep wo fp32 -> Wt[tap][co][ci] bf16 ------
__global__ __launch_bounds__(256) void wprep_kernel(
    const float* __restrict__ wo, unsigned short* __restrict__ Wt)
{
    const int i = blockIdx.x * 256 + threadIdx.x;     // 9*128*128 = 147456
    const int tap = i >> 14;
    const int rem = i & 16383;
    const int co  = rem >> 7;
    const int ci  = rem & 127;
    Wt[i] = f2bf(wo[(size_t)(co * CH + ci) * 9 + tap]);
}

// ---------------- Kernel 5b: 3x3 dense conv, 2-row blocks, swizzled LDS -------
// 512 threads (8 waves: 2 co-halves x 4 px-quarters over 256 px = 2 rows).
// sA: all 4 input rows resident (staged once); sW: one (tap,kh) 128x64 slice,
// T14 async prefetch (global->reg early, ds_write after barrier).
// XOR swizzle byte^=((x&7)<<4) on both tiles (no padding, conflict-spread).
__global__ __launch_bounds__(512, 2) void conv3x3_mfma_kernel(
    const unsigned short* __restrict__ At, const unsigned short* __restrict__ Wt,
    const float* __restrict__ bo, float* __restrict__ out)
{
    __shared__ __align__(16) char smem[149504];       // sA 133120 + sW 16384

    // XCD-bijective swizzle: 512 blocks, 8 XCDs -> XCD c owns batch c entirely
    const int w    = ((blockIdx.x & 7) << 6) | (blockIdx.x >> 3);
    const int yp   = w & 63;
    const int b    = w >> 6;
    const int y0   = yp << 1;

    const int tid  = threadIdx.x;
    const int wave = tid >> 6;
    const int lane = tid & 63;
    const int lx   = lane & 15;
    const int qd   = lane >> 4;
    const int m0   = (wave & 1) << 6;       // co half
    const int n0   = (wave >> 1) << 6;      // px quarter
    const int rsel = n0 >> 7;               // output row within pair (0/1)
    const int xb   = n0 & 64;               // x base within row

    const int j0 = tid, j1 = tid + 512;     // weight 16B-unit indices (0..1023)
    const int co0 = j0 >> 3, cu0 = j0 & 7;
    const int co1 = j1 >> 3, cu1 = j1 & 7;
    const unsigned swo0 = (unsigned)((co0 * 128 + cu0 * 16) ^ ((co0 & 7) << 4)) + 133120u;
    const unsigned swo1 = (unsigned)((co1 * 128 + cu1 * 16) ^ ((co1 & 7) << 4)) + 133120u;

    // prologue: issue slice-0 weight loads (tap0, kh0)
    float4 nwa = *(const float4*)&Wt[(size_t)co0 * 128 + cu0 * 8];
    float4 nwb = *(const float4*)&Wt[(size_t)co1 * 128 + cu1 * 8];

    // stage sA: 4 input rows [r][x'=x+1][ci], swizzled; zero halo cols + OOB rows
    const size_t abase = (size_t)b * HWSZ * CH;
    if (tid < 128) {
        const int r  = tid >> 5;
        const int cu = tid & 31;
        const int xp = (cu & 16) ? 129 : 0;
        const int u  = cu & 15;
        const unsigned off = (unsigned)(r * 33280 + xp * 256 + u * 16) ^ (((unsigned)xp & 7u) << 4);
        *(float4*)(smem + off) = make_float4(0.f, 0.f, 0.f, 0.f);
    }
    for (int i = tid; i < 8192; i += 512) {
        const int r   = i >> 11;
        const int rem = i & 2047;
        const int xx  = rem >> 4;
        const int u   = rem & 15;
        const int gy  = y0 - 1 + r;
        float4 v = make_float4(0.f, 0.f, 0.f, 0.f);
        if ((unsigned)gy < HH)
            v = *(const float4*)&At[abase + (size_t)gy * WW * CH + xx * CH + u * 8];
        const int xp = xx + 1;
        const unsigned off = (unsigned)(r * 33280 + xp * 256 + u * 16) ^ (((unsigned)xp & 7u) << 4);
        *(float4*)(smem + off) = v;
    }
    // write slice 0, then issue slice-1 loads
    *(float4*)(smem + swo0) = nwa;
    *(float4*)(smem + swo1) = nwb;
    nwa = *(const float4*)&Wt[(size_t)co0 * 128 + 64 + cu0 * 8];   // tap0, kh1
    nwb = *(const float4*)&Wt[(size_t)co1 * 128 + 64 + cu1 * 8];

    // bias-initialized accumulators
    f32x4 acc[4][4];
    #pragma unroll
    for (int mi = 0; mi < 4; ++mi) {
        f32x4 bv;
        #pragma unroll
        for (int r = 0; r < 4; ++r) bv[r] = bo[m0 + mi * 16 + qd * 4 + r];
        #pragma unroll
        for (int ni = 0; ni < 4; ++ni) acc[mi][ni] = bv;
    }

    __syncthreads();

    #pragma unroll 1
    for (int s = 0; s < 18; ++s) {
        const int tap = s >> 1;
        const int dy  = (tap * 11) >> 5;        // tap/3
        const int txc = tap - dy * 3;           // tap%3
        const int kh  = s & 1;
        const int ra  = rsel + dy;

        #pragma unroll
        for (int ks = 0; ks < 2; ++ks) {
            const int wkb = ks * 64 + qd * 16;            // ci-byte in sW slice
            const int akb = kh * 128 + ks * 64 + qd * 16; // ci-byte in sA row
            bf16x8 a[4], bfr[4];
            #pragma unroll
            for (int mi = 0; mi < 4; ++mi) {
                const int co = m0 + mi * 16 + lx;
                a[mi] = *(const bf16x8*)(smem + 133120u +
                        (unsigned)((co * 128 + wkb) ^ ((co & 7) << 4)));
            }
            #pragma unroll
            for (int ni = 0; ni < 4; ++ni) {
                const int xp = xb + ni * 16 + lx + txc;   // 0..129
                const unsigned off = (unsigned)(ra * 33280 + xp * 256 + akb)
                                   ^ (((unsigned)xp & 7u) << 4);
                bfr[ni] = *(const bf16x8*)(smem + off);
            }
            #pragma unroll
            for (int mi = 0; mi < 4; ++mi)
                #pragma unroll
                for (int ni = 0; ni < 4; ++ni)
                    acc[mi][ni] = __builtin_amdgcn_mfma_f32_16x16x32_bf16(
                        a[mi], bfr[ni], acc[mi][ni], 0, 0, 0);
        }
        __syncthreads();
        if (s < 17) {
            *(float4*)(smem + swo0) = nwa;     // slice s+1 into sW
            *(float4*)(smem + swo1) = nwb;
            if (s < 16) {
                const int s2 = s + 2;
                const size_t gb = (size_t)(s2 >> 1) * 16384 + (s2 & 1) * 64;
                nwa = *(const float4*)&Wt[gb + co0 * 128 + cu0 * 8];
                nwb = *(const float4*)&Wt[gb + co1 * 128 + cu1 * 8];
            }
            __syncthreads();
        }
    }

    // epilogue: out[b][co][y0+rsel][x]
    const int gy = y0 + rsel;
    const size_t obase = (size_t)b * CH * HWSZ + (size_t)gy * WW + xb;
    #pragma unroll
    for (int mi = 0; mi < 4; ++mi) {
        #pragma unroll
        for (int r = 0; r < 4; ++r) {
            const int co = m0 + mi * 16 + qd * 4 + r;
            float* orow = out + obase + (size_t)co * HWSZ;
            #pragma unroll
            for (int ni = 0; ni < 4; ++ni)
                orow[ni * 16 + lx] = acc[mi][ni][r];
        }
    }
}

extern "C" void kernel_launch(void* const* d_in, const int* in_sizes, int n_in,
                              void* d_out, int out_size, void* d_ws, size_t ws_size,
                              hipStream_t stream)
{
    const float* x  = (const float*)d_in[0];
    const float* wq = (const float*)d_in[1];
    const float* bq = (const float*)d_in[2];
    const float* wk = (const float*)d_in[3];
    const float* bk = (const float*)d_in[4];
    const float* wv = (const float*)d_in[5];
    const float* bv = (const float*)d_in[6];
    const float* wo = (const float*)d_in[7];
    const float* bo = (const float*)d_in[8];

    char* ws = (char*)d_ws;
    unsigned short* Qb    = (unsigned short*)(ws);                        // 32 MiB
    unsigned short* Kb    = (unsigned short*)(ws + (size_t)33554432);     // 32 MiB
    unsigned short* Vb    = (unsigned short*)(ws + (size_t)67108864);     // 32 MiB
    float*          Spart = (float*)        (ws + (size_t)100663296);     // 32 MiB
    unsigned short* Pb    = (unsigned short*)(ws + (size_t)134217728);    // 2 MiB
    unsigned short* At    = (unsigned short*)(ws + (size_t)136314880);    // 32 MiB -> ends 169869312
    unsigned short* Wt    = (unsigned short*)(ws + (size_t)169869312);    // 288 KiB
    _Float16*       Tp    = (_Float16*)      (ws + (size_t)100663296);    // aliases Spart head (dead by then)

    toeplitz_prep_kernel<<<864, 256, 0, stream>>>(wq, wk, wv, Tp);
    dwconv_qkv_mfma_kernel<<<BATCH * CH, 256, 0, stream>>>(x, bq, bk, bv, Tp, Qb, Kb, Vb);
    wprep_kernel<<<576, 256, 0, stream>>>(wo, Wt);
    qk_mfma_kernel<<<64 * 8, 256, 0, stream>>>(Qb, Kb, Spart);
    softmax_kernel<<<2048, 256, 0, stream>>>(Spart, Pb);
    pv_mfma_kernel<<<64 * 16, 256, 0, stream>>>(Pb, Vb, At);
    conv3x3_mfma_kernel<<<BATCH * 64, 512, 0, stream>>>(At, Wt, bo, (float*)d_out);
}